// Round 1
// baseline (434.516 us; speedup 1.0000x reference)
//
#include <hip/hip_runtime.h>

// TTLinearR: y = x @ W^T + b where W (4096x4096) is TT with ranks [1,64,64,64,64,64,1].
// Key insight: W = Amat(4096,64) @ Bmat(64,4096)  (rank-64 factorization at the middle rank).
//   Amat = ((c0r(16,64)@c1r(64,1024)).reshape(256,64)@c2r(64,1024)).reshape(4096,64)
//   Bmat = c3r(1024,64+contract) chain from the right:
//     S3(1024,16) = c4.reshape(1024,64) @ c5.reshape(64,16)   -> viewed (64,256)
//     Bmat(1024,256) = c3.reshape(1024,64) @ S3v(64,256)      -> viewed (64,4096)
// Then: t(8192,64) = x @ Bmat^T ; y = t @ Amat^T + b.
// Total ~8.6 GFLOP vs 275 GFLOP dense; memory floor ~256 MB (~41 us).

#define TOK 8192
#define DIN 4096
#define DOUT 4096
#define RNK 64

// C[M][N] = A[M][64] @ B[64][N]; one thread per output element. M*N must be /256.
__global__ void mm64_kernel(const float* __restrict__ A, const float* __restrict__ B,
                            float* __restrict__ C, int N) {
  int idx = blockIdx.x * 256 + threadIdx.x;
  int m = idx / N;
  int n = idx - m * N;
  const float* a = A + m * 64;
  float acc = 0.f;
#pragma unroll
  for (int k = 0; k < 64; ++k) acc += a[k] * B[k * N + n];
  C[idx] = acc;
}

// C[m][n] (+)= sum_k Am[m*ldA+k] * Bm[n*ldB+k]   (B given transposed, K inner both)
// 64x64 block tile, 256 threads, 4x4 micro-tile per thread, K staged 64 at a time.
// flags: 1 = atomicAdd into C (split-K), 2 = add bias[n].
__global__ __launch_bounds__(256)
void gemm_bt_f32(const float* __restrict__ Am, const float* __restrict__ Bm,
                 const float* __restrict__ bias, float* __restrict__ C,
                 int ldA, int ldB, int ldC, int kChunk, int flags) {
  __shared__ float As[64][64];  // [k][m] — transposed so compute reads are float4
  __shared__ float Bs[64][64];  // [k][n]
  const int tid = threadIdx.x;
  const int m0 = blockIdx.y * 64, n0 = blockIdx.x * 64;
  const int tm = tid >> 4, tn = tid & 15;
  float acc[4][4] = {};
  const int kStart = blockIdx.z * kChunk;
  for (int k0 = kStart; k0 < kStart + kChunk; k0 += 64) {
    // stage 64 rows x 64 k of each operand; global reads are coalesced float4,
    // LDS writes transpose (16-way bank conflict, but ~200cyc vs ~2000cyc compute)
#pragma unroll
    for (int j = 0; j < 4; ++j) {
      int f4 = tid + j * 256;
      int mr = f4 >> 4, kc = f4 & 15;
      float4 va = *(const float4*)&Am[(size_t)(m0 + mr) * ldA + k0 + kc * 4];
      As[kc * 4 + 0][mr] = va.x; As[kc * 4 + 1][mr] = va.y;
      As[kc * 4 + 2][mr] = va.z; As[kc * 4 + 3][mr] = va.w;
      float4 vb = *(const float4*)&Bm[(size_t)(n0 + mr) * ldB + k0 + kc * 4];
      Bs[kc * 4 + 0][mr] = vb.x; Bs[kc * 4 + 1][mr] = vb.y;
      Bs[kc * 4 + 2][mr] = vb.z; Bs[kc * 4 + 3][mr] = vb.w;
    }
    __syncthreads();
#pragma unroll 8
    for (int kc = 0; kc < 64; ++kc) {
      float4 a4 = *(const float4*)&As[kc][tm * 4];  // broadcast within wave, conflict-free
      float4 b4 = *(const float4*)&Bs[kc][tn * 4];  // 2-way alias = free
      float av[4] = {a4.x, a4.y, a4.z, a4.w};
      float bv[4] = {b4.x, b4.y, b4.z, b4.w};
#pragma unroll
      for (int i = 0; i < 4; ++i)
#pragma unroll
        for (int j = 0; j < 4; ++j) acc[i][j] += av[i] * bv[j];
    }
    __syncthreads();
  }
  if (flags & 1) {
#pragma unroll
    for (int i = 0; i < 4; ++i)
#pragma unroll
      for (int j = 0; j < 4; ++j)
        atomicAdd(&C[(size_t)(m0 + tm * 4 + i) * ldC + n0 + tn * 4 + j], acc[i][j]);
  } else {
    float4 bv4 = make_float4(0.f, 0.f, 0.f, 0.f);
    if (flags & 2) bv4 = *(const float4*)&bias[n0 + tn * 4];
#pragma unroll
    for (int i = 0; i < 4; ++i) {
      float4 o;
      o.x = acc[i][0] + bv4.x; o.y = acc[i][1] + bv4.y;
      o.z = acc[i][2] + bv4.z; o.w = acc[i][3] + bv4.w;
      *(float4*)&C[(size_t)(m0 + tm * 4 + i) * ldC + n0 + tn * 4] = o;  // coalesced
    }
  }
}

extern "C" void kernel_launch(void* const* d_in, const int* in_sizes, int n_in,
                              void* d_out, int out_size, void* d_ws, size_t ws_size,
                              hipStream_t stream) {
  const float* c0 = (const float*)d_in[0];
  const float* c1 = (const float*)d_in[1];
  const float* c2 = (const float*)d_in[2];
  const float* c3 = (const float*)d_in[3];
  const float* c4 = (const float*)d_in[4];
  const float* c5 = (const float*)d_in[5];
  const float* x  = (const float*)d_in[6];
  const float* bias = (const float*)d_in[7];
  float* out = (float*)d_out;

  char* ws = (char*)d_ws;
  float* t    = (float*)(ws);                          // 8192*64 f32 = 2 MB
  float* Amat = (float*)(ws + (2u << 20));             // 4096*64  = 1 MB
  float* Bmat = (float*)(ws + (3u << 20));             // 64*4096  = 1 MB
  float* S1   = (float*)(ws + (4u << 20));             // 16*1024  = 64 KB
  float* S3   = (float*)(ws + (4u << 20) + (1u << 17)); // 1024*16 = 64 KB

  // t must be zeroed every call (ws is re-poisoned to 0xAA before each launch)
  hipMemsetAsync(t, 0, (size_t)TOK * RNK * sizeof(float), stream);

  // --- build the rank-64 factorization (all tiny: ~70 MFLOP total) ---
  // S1(16,1024)  = c0.reshape(16,64) @ c1.reshape(64,1024)
  mm64_kernel<<<(16 * 1024) / 256, 256, 0, stream>>>(c0, c1, S1, 1024);
  // Amat(256,1024)->view(4096,64) = S1.reshape(256,64) @ c2.reshape(64,1024)
  mm64_kernel<<<(256 * 1024) / 256, 256, 0, stream>>>(S1, c2, Amat, 1024);
  // S3(1024,16)->view(64,256) = c4.reshape(1024,64) @ c5.reshape(64,16)
  mm64_kernel<<<(1024 * 16) / 256, 256, 0, stream>>>(c4, c5, S3, 16);
  // Bmat(1024,256)->view(64,4096) = c3.reshape(1024,64) @ S3view(64,256)
  mm64_kernel<<<(1024 * 256) / 256, 256, 0, stream>>>(c3, S3, Bmat, 256);

  // --- t(8192,64) = x(8192,4096) @ Bmat(64,4096)^T, split-K=4, atomic ---
  gemm_bt_f32<<<dim3(1, TOK / 64, 4), 256, 0, stream>>>(
      x, Bmat, nullptr, t, DIN, DIN, RNK, DIN / 4, /*flags=*/1);

  // --- y(8192,4096) = t(8192,64) @ Amat(4096,64)^T + bias ---
  gemm_bt_f32<<<dim3(DOUT / 64, TOK / 64, 1), 256, 0, stream>>>(
      t, Amat, bias, out, RNK, RNK, DOUT, RNK, /*flags=*/2);
}

// Round 2
// 288.724 us; speedup vs baseline: 1.5050x; 1.5050x over previous
//
#include <hip/hip_runtime.h>

// TTLinearR: y = x @ W^T + b, W (4096x4096) = TT ranks [1,64,64,64,64,64,1].
// W = Amat(4096,64) @ Bmat(64,4096) (rank-64 middle factorization):
//   Amat = ((c0r(16,64)@c1r(64,1024)).reshape(256,64)@c2r(64,1024)).reshape(4096,64)
//   S3(1024,16) = c4r(1024,64)@c5r(64,16); Bmat(1024,256) = c3r(1024,64)@S3view(64,256)
// y = (x @ Bmat^T) @ Amat^T + b.  ~8.6 GFLOP; memory floor ~260 MB (~42 us).
// Tolerance is 2% relative (harness compares in bf16) -> bf16 MFMA path.

#define TOK 8192
#define DIN 4096
#define DOUT 4096
#define RNK 64

typedef __bf16 bf16x8 __attribute__((ext_vector_type(8)));
typedef float f32x4 __attribute__((ext_vector_type(4)));

__device__ __forceinline__ unsigned short f2bf(float f) {
  unsigned int u = __float_as_uint(f);
  u += 0x7FFFu + ((u >> 16) & 1u);  // RNE
  return (unsigned short)(u >> 16);
}

// ---------------- chain: C[M][N] = A[M][64] @ B[64][N], tiny ----------------
__global__ void mm64_kernel(const float* __restrict__ A, const float* __restrict__ B,
                            float* __restrict__ C, int N) {
  int idx = blockIdx.x * 256 + threadIdx.x;
  int m = idx / N;
  int n = idx - m * N;
  const float* a = A + m * 64;
  float acc = 0.f;
#pragma unroll
  for (int k = 0; k < 64; ++k) acc += a[k] * B[k * N + n];
  C[idx] = acc;
}

// ---------------- GEMM1: t(8192,64) += x(8192,4096) @ Bmat(64,4096)^T -------
// grid (1, 128, 8): by = 64-token tile, bz = K-split (512 K each, 4 stages of 128).
// fp32 atomic accumulate into t.
#define G1_SX 136  // 128 + 8 bf16 pad: even bank spread for b128 frag reads
__global__ __launch_bounds__(256, 2)
void gemm1_mfma(const float* __restrict__ x, const float* __restrict__ Bmat,
                float* __restrict__ t) {
  __shared__ unsigned short xs[64 * G1_SX];
  __shared__ unsigned short bs[64 * G1_SX];
  const int tid = threadIdx.x;
  const int m0 = blockIdx.y * 64;
  const int lane = tid & 63, wv = tid >> 6;
  const int r = lane & 15, q = lane >> 4;

  f32x4 acc[4];
#pragma unroll
  for (int j = 0; j < 4; ++j) acc[j] = (f32x4){0.f, 0.f, 0.f, 0.f};

  for (int s = 0; s < 4; ++s) {
    const int kbase = blockIdx.z * 512 + s * 128;
    // stage x-tile (64x128) and B-tile (64x128), fp32 -> bf16
#pragma unroll
    for (int j = 0; j < 8; ++j) {
      int f = j * 256 + tid;
      int row = f >> 5, c4 = f & 31;
      float4 vx = *(const float4*)&x[(size_t)(m0 + row) * DIN + kbase + c4 * 4];
      ushort4 hx = {f2bf(vx.x), f2bf(vx.y), f2bf(vx.z), f2bf(vx.w)};
      *(ushort4*)&xs[row * G1_SX + c4 * 4] = hx;
      float4 vb = *(const float4*)&Bmat[(size_t)row * DIN + kbase + c4 * 4];
      ushort4 hb = {f2bf(vb.x), f2bf(vb.y), f2bf(vb.z), f2bf(vb.w)};
      *(ushort4*)&bs[row * G1_SX + c4 * 4] = hb;
    }
    __syncthreads();
#pragma unroll
    for (int s32 = 0; s32 < 4; ++s32) {
      bf16x8 a = *(const bf16x8*)&xs[(wv * 16 + r) * G1_SX + s32 * 32 + q * 8];
#pragma unroll
      for (int j = 0; j < 4; ++j) {
        bf16x8 b = *(const bf16x8*)&bs[(j * 16 + r) * G1_SX + s32 * 32 + q * 8];
        acc[j] = __builtin_amdgcn_mfma_f32_16x16x32_bf16(a, b, acc[j], 0, 0, 0);
      }
    }
    __syncthreads();
  }
  // C/D: col = lane&15 (rank), row = q*4 + reg (token)
#pragma unroll
  for (int j = 0; j < 4; ++j)
#pragma unroll
    for (int i = 0; i < 4; ++i)
      atomicAdd(&t[(size_t)(m0 + wv * 16 + q * 4 + i) * RNK + j * 16 + r], acc[j][i]);
}

// ---------------- GEMM2: y(8192,4096) = t(8192,64) @ Amat(4096,64)^T + b ----
// grid (32, 64): bx = 128-col tile, by = 128-token tile. K=64 staged once.
#define G2_S 72  // 64 + 8 bf16 pad
__global__ __launch_bounds__(256, 2)
void gemm2_mfma(const float* __restrict__ t, const float* __restrict__ Amat,
                const float* __restrict__ bias, float* __restrict__ out) {
  __shared__ unsigned short ts[128 * G2_S];
  __shared__ unsigned short as_[128 * G2_S];
  const int tid = threadIdx.x;
  const int m0 = blockIdx.y * 128, n0 = blockIdx.x * 128;
  const int lane = tid & 63, wv = tid >> 6;
  const int r = lane & 15, q = lane >> 4;

  // stage t-tile (128x64) and Amat-tile (128x64), fp32 -> bf16
#pragma unroll
  for (int j = 0; j < 8; ++j) {
    int f = j * 256 + tid;
    int row = f >> 4, c4 = f & 15;
    float4 vt = *(const float4*)&t[(size_t)(m0 + row) * RNK + c4 * 4];
    ushort4 ht = {f2bf(vt.x), f2bf(vt.y), f2bf(vt.z), f2bf(vt.w)};
    *(ushort4*)&ts[row * G2_S + c4 * 4] = ht;
    float4 va = *(const float4*)&Amat[(size_t)(n0 + row) * RNK + c4 * 4];
    ushort4 ha = {f2bf(va.x), f2bf(va.y), f2bf(va.z), f2bf(va.w)};
    *(ushort4*)&as_[row * G2_S + c4 * 4] = ha;
  }
  __syncthreads();

  const int mw = (wv >> 1) * 64, nw = (wv & 1) * 64;
  f32x4 acc[4][4];
#pragma unroll
  for (int i = 0; i < 4; ++i)
#pragma unroll
    for (int j = 0; j < 4; ++j) acc[i][j] = (f32x4){0.f, 0.f, 0.f, 0.f};

#pragma unroll
  for (int s32 = 0; s32 < 2; ++s32) {
    bf16x8 a[4], b[4];
#pragma unroll
    for (int i = 0; i < 4; ++i)
      a[i] = *(const bf16x8*)&ts[(mw + i * 16 + r) * G2_S + s32 * 32 + q * 8];
#pragma unroll
    for (int j = 0; j < 4; ++j)
      b[j] = *(const bf16x8*)&as_[(nw + j * 16 + r) * G2_S + s32 * 32 + q * 8];
#pragma unroll
    for (int i = 0; i < 4; ++i)
#pragma unroll
      for (int j = 0; j < 4; ++j)
        acc[i][j] = __builtin_amdgcn_mfma_f32_16x16x32_bf16(a[i], b[j], acc[i][j], 0, 0, 0);
  }

  float bb[4];
#pragma unroll
  for (int j = 0; j < 4; ++j) bb[j] = bias[n0 + nw + j * 16 + r];

#pragma unroll
  for (int i = 0; i < 4; ++i)
#pragma unroll
    for (int reg = 0; reg < 4; ++reg) {
      size_t rowg = (size_t)(m0 + mw + i * 16 + q * 4 + reg) * DOUT;
#pragma unroll
      for (int j = 0; j < 4; ++j)
        out[rowg + n0 + nw + j * 16 + r] = acc[i][j][reg] + bb[j];
    }
}

extern "C" void kernel_launch(void* const* d_in, const int* in_sizes, int n_in,
                              void* d_out, int out_size, void* d_ws, size_t ws_size,
                              hipStream_t stream) {
  const float* c0 = (const float*)d_in[0];
  const float* c1 = (const float*)d_in[1];
  const float* c2 = (const float*)d_in[2];
  const float* c3 = (const float*)d_in[3];
  const float* c4 = (const float*)d_in[4];
  const float* c5 = (const float*)d_in[5];
  const float* x  = (const float*)d_in[6];
  const float* bias = (const float*)d_in[7];
  float* out = (float*)d_out;

  char* ws = (char*)d_ws;
  float* t    = (float*)(ws);                            // 8192*64 f32 = 2 MB
  float* Amat = (float*)(ws + (2u << 20));               // 4096*64  = 1 MB
  float* Bmat = (float*)(ws + (3u << 20));               // 64*4096  = 1 MB
  float* S1   = (float*)(ws + (4u << 20));               // 16*1024  = 64 KB
  float* S3   = (float*)(ws + (4u << 20) + (1u << 17));  // 1024*16  = 64 KB

  hipMemsetAsync(t, 0, (size_t)TOK * RNK * sizeof(float), stream);

  // rank-64 factorization chain (tiny)
  mm64_kernel<<<(16 * 1024) / 256, 256, 0, stream>>>(c0, c1, S1, 1024);
  mm64_kernel<<<(256 * 1024) / 256, 256, 0, stream>>>(S1, c2, Amat, 1024);
  mm64_kernel<<<(1024 * 16) / 256, 256, 0, stream>>>(c4, c5, S3, 16);
  mm64_kernel<<<(1024 * 256) / 256, 256, 0, stream>>>(c3, S3, Bmat, 256);

  // t = x @ Bmat^T  (read-bound: 128 MB of x), bf16 MFMA, split-K=8 + atomics
  gemm1_mfma<<<dim3(1, TOK / 64, 8), 256, 0, stream>>>(x, Bmat, t);

  // y = t @ Amat^T + b  (write-bound: 128 MB of y), bf16 MFMA
  gemm2_mfma<<<dim3(DOUT / 128, TOK / 128), 256, 0, stream>>>(t, Amat, bias, out);
}